// Round 3
// baseline (495.123 us; speedup 1.0000x reference)
//
#include <hip/hip_runtime.h>
#include <hip/hip_bf16.h>

// GNNLayer: B=8, N=200, D=128, fp32 I/O. Recompute-Ce two-pass, bf16 MFMA.
// R3: fragment-ordered Cw LDS (zero bank conflicts), 1 j-tile per block
// (grid 6400, 4x block parallelism), atomic partial reduction for agg/BN.

#define B_ 8
#define N_ 200
#define D_ 128
#define BN_ (B_*N_)      // 1600
#define HN_ (BN_*D_)     // 204800

typedef __attribute__((ext_vector_type(8))) short short8v;
typedef __attribute__((ext_vector_type(4))) short short4v;
typedef __attribute__((ext_vector_type(4))) float float4v;
typedef __attribute__((ext_vector_type(4))) unsigned int uint4v;

__device__ __forceinline__ unsigned short f2b(float f) {
  unsigned u = __float_as_uint(f);
  u += 0x7FFFu + ((u >> 16) & 1u);
  return (unsigned short)(u >> 16);
}

// ---------------------------------------------------------------------------
// K0: blocks 0..99: Uh/Vh/Ah/Bh = h @ {U,V,A,B}w.T + bias
//     blocks 100..107: convert Cw -> bf16 in MFMA-fragment order:
//     Cwf[((t*4+l)*64 + lane)*8 + i] = bf16(Cw[t*16+(lane&15)][l*32+(lane>>4)*8+i])
// ---------------------------------------------------------------------------
__global__ __launch_bounds__(256) void prelin_kernel(
    const float* __restrict__ h,
    const float* __restrict__ Uw, const float* __restrict__ Ub,
    const float* __restrict__ Vw, const float* __restrict__ Vb,
    const float* __restrict__ Aw, const float* __restrict__ Ab,
    const float* __restrict__ Bw, const float* __restrict__ Bb,
    const float* __restrict__ Cw,
    float* __restrict__ Uh, float* __restrict__ Vh,
    float* __restrict__ Ah, float* __restrict__ Bh,
    unsigned short* __restrict__ Cwf) {
  const int tid = threadIdx.x;
  if (blockIdx.x >= 100) {
    const int slot = (blockIdx.x - 100) * 256 + tid;   // 0..2047
    const int fr = slot >> 6, ln = slot & 63;
    const int t = fr >> 2, l = fr & 3, cc = ln & 15, qq = ln >> 4;
    const float* src = Cw + (t * 16 + cc) * 128 + l * 32 + qq * 8;
    float4v v0 = *(const float4v*)src;
    float4v v1 = *(const float4v*)(src + 4);
    short8v s;
    s[0] = (short)f2b(v0.x); s[1] = (short)f2b(v0.y);
    s[2] = (short)f2b(v0.z); s[3] = (short)f2b(v0.w);
    s[4] = (short)f2b(v1.x); s[5] = (short)f2b(v1.y);
    s[6] = (short)f2b(v1.z); s[7] = (short)f2b(v1.w);
    *(short8v*)(Cwf + (size_t)slot * 8) = s;
    return;
  }
  const int r0 = blockIdx.x * 16;
  __shared__ float hs[16][128];
  for (int k = 0; k < 2; k++) {
    int g = k * 256 + tid;
    int row = g >> 5, col4 = g & 31;
    *(float4v*)&hs[row][col4 * 4] =
        *(const float4v*)(h + (size_t)(r0 + row) * D_ + col4 * 4);
  }
  __syncthreads();
  const int c0 = tid, c1 = tid + 256;
  const float* w0 = (c0 < 128) ? (Uw + c0 * 128) : (Vw + (c0 - 128) * 128);
  const float  b0 = (c0 < 128) ? Ub[c0] : Vb[c0 - 128];
  const float* w1 = (c1 < 384) ? (Aw + (c1 - 256) * 128) : (Bw + (c1 - 384) * 128);
  const float  b1 = (c1 < 384) ? Ab[c1 - 256] : Bb[c1 - 384];
  float acc0[16], acc1[16];
#pragma unroll
  for (int r = 0; r < 16; r++) { acc0[r] = 0.f; acc1[r] = 0.f; }
  for (int k = 0; k < 128; k += 4) {
    float4v w0v = *(const float4v*)(w0 + k);
    float4v w1v = *(const float4v*)(w1 + k);
#pragma unroll
    for (int r = 0; r < 16; r++) {
      float4v hv = *(const float4v*)&hs[r][k];
      acc0[r] = fmaf(hv.x, w0v.x, fmaf(hv.y, w0v.y, fmaf(hv.z, w0v.z, fmaf(hv.w, w0v.w, acc0[r]))));
      acc1[r] = fmaf(hv.x, w1v.x, fmaf(hv.y, w1v.y, fmaf(hv.z, w1v.z, fmaf(hv.w, w1v.w, acc1[r]))));
    }
  }
  float* dst0 = (c0 < 128) ? Uh : Vh; const int cc0 = c0 & 127;
  float* dst1 = (c1 < 384) ? Ah : Bh; const int cc1 = (c1 - 256) & 127;
#pragma unroll
  for (int r = 0; r < 16; r++) {
    dst0[(size_t)(r0 + r) * D_ + cc0] = acc0[r] + b0;
    dst1[(size_t)(r0 + r) * D_ + cc1] = acc1[r] + b1;
  }
}

// ---------------------------------------------------------------------------
// K1/K4: one 64-row j-tile per block. blk -> (bi = blk>>2, jt = blk&3).
// e-fragments direct global->register; Cw fragment-ordered in LDS (conflict-
// free ds_read_b128). MODE 0: D = e.Cw^T, sigmoid-gate agg + BN sums via
// shfl + atomicAdd partials. MODE 1: D = Cw.e^T, float4 epilogue + store.
// ---------------------------------------------------------------------------
template <int MODE>
__global__ __launch_bounds__(256, 4) void gemm_pass(
    const float* __restrict__ e, const unsigned short* __restrict__ Cwf,
    const float* __restrict__ Cb, const float* __restrict__ Ah,
    const float* __restrict__ Bh, const float* __restrict__ Vh,
    float* __restrict__ agg, float* __restrict__ psum, float* __restrict__ psumsq,
    const float* __restrict__ scale_e, const float* __restrict__ shift_e,
    float* __restrict__ e_out) {
  const int tid = threadIdx.x;
  const int blk = blockIdx.x;
  const int bi = blk >> 2, jt = blk & 3;
  const int b = bi / N_;
  const int lane = tid & 63, wz = tid >> 6;
  const int c = lane & 15, q = lane >> 4;
  const int j0 = jt * 64;

  __shared__ __align__(16) unsigned short Bs[16384];  // 32 frags x 64 lanes x 8
  __shared__ float base_s[128];
  __shared__ float ss_s[256];

  // issue e-fragment loads first (overlap with Cw staging)
  const int jrow = j0 + wz * 16 + c;
  const bool rok = (jrow < N_);
  const float* ep = e + ((size_t)bi * N_ + jrow) * D_ + q * 8;
  float4v ef[8];
#pragma unroll
  for (int l = 0; l < 4; l++) {
    ef[2 * l]     = rok ? *(const float4v*)(ep + l * 32)     : (float4v){0.f,0.f,0.f,0.f};
    ef[2 * l + 1] = rok ? *(const float4v*)(ep + l * 32 + 4) : (float4v){0.f,0.f,0.f,0.f};
  }

  // stage fragment-ordered Cw: 32768 B = 2048 uint4 chunks
  {
    const uint4v* bsrc = (const uint4v*)Cwf;
    uint4v* bdst = (uint4v*)Bs;
#pragma unroll
    for (int k2 = 0; k2 < 8; k2++) bdst[k2 * 256 + tid] = bsrc[k2 * 256 + tid];
  }
  if (tid < 128) {
    base_s[tid] = Cb[tid] + Bh[(size_t)bi * D_ + tid];
    if (MODE == 1) { ss_s[tid] = scale_e[tid]; ss_s[128 + tid] = shift_e[tid]; }
  }

  // convert e fragments fp32 -> bf16
  short8v av[4];
#pragma unroll
  for (int l = 0; l < 4; l++) {
    float4v v0 = ef[2 * l], v1 = ef[2 * l + 1];
    short8v s;
    s[0] = (short)f2b(v0.x); s[1] = (short)f2b(v0.y);
    s[2] = (short)f2b(v0.z); s[3] = (short)f2b(v0.w);
    s[4] = (short)f2b(v1.x); s[5] = (short)f2b(v1.y);
    s[6] = (short)f2b(v1.z); s[7] = (short)f2b(v1.w);
    av[l] = s;
  }
  __syncthreads();

  float4v acc[8];
#pragma unroll
  for (int t = 0; t < 8; t++) acc[t] = (float4v){0.f, 0.f, 0.f, 0.f};
#pragma unroll
  for (int l = 0; l < 4; l++) {
#pragma unroll
    for (int t = 0; t < 8; t++) {
      short8v cw = *(const short8v*)&Bs[(((t * 4 + l) * 64) + lane) * 8];
      if (MODE == 0)
        acc[t] = __builtin_amdgcn_mfma_f32_16x16x32_bf16(av[l], cw, acc[t], 0, 0, 0);
      else
        acc[t] = __builtin_amdgcn_mfma_f32_16x16x32_bf16(cw, av[l], acc[t], 0, 0, 0);
    }
  }

  if (MODE == 0) {
    // D layout: n = t*16+c, j = j0 + wz*16 + q*4 + r
    const float* AhB = Ah + (size_t)b * N_ * D_;
    const float* VhB = Vh + (size_t)b * N_ * D_;
#pragma unroll
    for (int t = 0; t < 8; t++) {
      const int n = t * 16 + c;
      const float bse = base_s[n];
      float at = 0.f, st = 0.f, qt = 0.f;
#pragma unroll
      for (int r = 0; r < 4; r++) {
        const int j = j0 + wz * 16 + q * 4 + r;
        if (j < N_) {
          float x = acc[t][r] + bse + AhB[(size_t)j * D_ + n];
          float g = __builtin_amdgcn_rcpf(1.0f + __expf(-x));
          at += g * VhB[(size_t)j * D_ + n];
          st += x; qt += x * x;
        }
      }
      at += __shfl_xor(at, 16); at += __shfl_xor(at, 32);
      st += __shfl_xor(st, 16); st += __shfl_xor(st, 32);
      qt += __shfl_xor(qt, 16); qt += __shfl_xor(qt, 32);
      if (lane < 16) {
        atomicAdd(&agg[(size_t)bi * D_ + n], at);
        atomicAdd(&psum[(size_t)bi * D_ + n], st);
        atomicAdd(&psumsq[(size_t)bi * D_ + n], qt);
      }
    }
  } else {
    // D layout: j = j0 + wz*16 + c (fixed), n = t*16 + q*4 + r -> float4
    const int j = j0 + wz * 16 + c;
    if (j < N_) {
      const float* AhB = Ah + (size_t)b * N_ * D_;
      const size_t rowoff = ((size_t)bi * N_ + j) * D_;
#pragma unroll
      for (int t = 0; t < 8; t++) {
        const int n4 = t * 16 + q * 4;
        float4v ah = *(const float4v*)(AhB + (size_t)j * D_ + n4);
        float4v bs4 = *(const float4v*)&base_s[n4];
        float4v sc4 = *(const float4v*)&ss_s[n4];
        float4v sh4 = *(const float4v*)&ss_s[128 + n4];
        float4v ein = *(const float4v*)(e + rowoff + n4);
        float4v o;
#pragma unroll
        for (int r = 0; r < 4; r++) {
          float x = acc[t][r] + bs4[r] + ah[r];
          float y = fmaxf(x * sc4[r] + sh4[r], 0.f);
          o[r] = ein[r] + y;
        }
        *(float4v*)(e_out + rowoff + n4) = o;
      }
    }
  }
}

// ---------------------------------------------------------------------------
// K2a: coalesced partial reduction of BN stats (100 blocks x 16 rows)
// ---------------------------------------------------------------------------
__global__ __launch_bounds__(256) void stats_part(
    const float* __restrict__ psum, const float* __restrict__ psumsq,
    const float* __restrict__ Uh, const float* __restrict__ agg,
    float* __restrict__ partial) {
  const int t = threadIdx.x, blk = blockIdx.x;
  const int cg = t & 31, rs = t >> 5;
  float4v ps = {0,0,0,0}, pq = {0,0,0,0}, hs = {0,0,0,0}, hq = {0,0,0,0};
#pragma unroll
  for (int p = 0; p < 2; p++) {
    const int row = blk * 16 + p * 8 + rs;
    const size_t off = (size_t)row * D_ + cg * 4;
    float4v a = *(const float4v*)(psum + off);
    float4v bq = *(const float4v*)(psumsq + off);
    float4v u = *(const float4v*)(Uh + off);
    float4v g = *(const float4v*)(agg + off);
    ps += a; pq += bq;
    float4v hv = u + g;
    hs += hv; hq += hv * hv;
  }
  __shared__ float4v red[4][8][32];
  red[0][rs][cg] = ps; red[1][rs][cg] = pq; red[2][rs][cg] = hs; red[3][rs][cg] = hq;
  __syncthreads();
  if (t < 128) {
    const int s = t >> 5, g = t & 31;
    float4v acc = red[s][0][g];
#pragma unroll
    for (int r = 1; r < 8; r++) acc += red[s][r][g];
    *(float4v*)(partial + (size_t)blk * 512 + s * 128 + g * 4) = acc;
  }
}

// ---------------------------------------------------------------------------
// K2b: final stats -> scale/shift (1 block, 128 threads)
// ---------------------------------------------------------------------------
__global__ __launch_bounds__(128) void stats_final(
    const float* __restrict__ partial,
    const float* __restrict__ gamma_h, const float* __restrict__ beta_h,
    const float* __restrict__ gamma_e, const float* __restrict__ beta_e,
    float* __restrict__ scale_e, float* __restrict__ shift_e,
    float* __restrict__ scale_h, float* __restrict__ shift_h) {
  const int n = threadIdx.x;
  float s = 0.f, sq = 0.f, hs = 0.f, hq = 0.f;
  for (int p = 0; p < 100; p++) {
    const float* base = partial + (size_t)p * 512;
    s += base[n]; sq += base[128 + n]; hs += base[256 + n]; hq += base[384 + n];
  }
  const float Me = 8.f * 200.f * 200.f;
  float mean = s / Me;
  float var = sq / Me - mean * mean;
  float sce = gamma_e[n] * rsqrtf(var + 1e-5f);
  scale_e[n] = sce; shift_e[n] = beta_e[n] - mean * sce;
  const float Mh = (float)BN_;
  float mh = hs / Mh;
  float vh = hq / Mh - mh * mh;
  float sch = gamma_h[n] * rsqrtf(vh + 1e-5f);
  scale_h[n] = sch; shift_h[n] = beta_h[n] - mh * sch;
}

// ---------------------------------------------------------------------------
// K3: h_out = h + relu((Uh+agg)*scale_h + shift_h)
// ---------------------------------------------------------------------------
__global__ __launch_bounds__(256) void hpath_kernel(
    const float* __restrict__ h, const float* __restrict__ Uh,
    const float* __restrict__ agg, const float* __restrict__ scale_h,
    const float* __restrict__ shift_h, float* __restrict__ h_out) {
  const int idx = blockIdx.x * 256 + threadIdx.x;
  float4v u = ((const float4v*)Uh)[idx];
  float4v a = ((const float4v*)agg)[idx];
  float4v hv = ((const float4v*)h)[idx];
  float4v sc = ((const float4v*)scale_h)[idx & 31];
  float4v sh = ((const float4v*)shift_h)[idx & 31];
  float4v o;
#pragma unroll
  for (int l = 0; l < 4; l++) {
    float y = fmaxf((u[l] + a[l]) * sc[l] + sh[l], 0.f);
    o[l] = hv[l] + y;
  }
  ((float4v*)h_out)[idx] = o;
}

// ---------------------------------------------------------------------------
extern "C" void kernel_launch(void* const* d_in, const int* in_sizes, int n_in,
                              void* d_out, int out_size, void* d_ws, size_t ws_size,
                              hipStream_t stream) {
  const float* h  = (const float*)d_in[0];
  const float* e  = (const float*)d_in[1];
  const float* Uw = (const float*)d_in[2];  const float* Ub = (const float*)d_in[3];
  const float* Vw = (const float*)d_in[4];  const float* Vb = (const float*)d_in[5];
  const float* Aw = (const float*)d_in[6];  const float* Ab = (const float*)d_in[7];
  const float* Bw = (const float*)d_in[8];  const float* Bb = (const float*)d_in[9];
  const float* Cw = (const float*)d_in[10]; const float* Cb = (const float*)d_in[11];
  const float* gamma_h = (const float*)d_in[12]; const float* beta_h = (const float*)d_in[13];
  const float* gamma_e = (const float*)d_in[14]; const float* beta_e = (const float*)d_in[15];

  float* ws = (float*)d_ws;
  float* Uh = ws + 0;
  float* Vh = ws + (size_t)HN_;
  float* Ah = ws + (size_t)HN_ * 2;
  float* Bh = ws + (size_t)HN_ * 3;
  float* agg = ws + (size_t)HN_ * 4;       // agg|psum|psumsq contiguous (memset)
  float* psum = ws + (size_t)HN_ * 5;
  float* psumsq = ws + (size_t)HN_ * 6;
  float* scale_e = ws + (size_t)HN_ * 7;
  float* shift_e = scale_e + 128;
  float* scale_h = scale_e + 256;
  float* shift_h = scale_e + 384;
  unsigned short* Cwf = (unsigned short*)(scale_e + 512);  // 16384 bf16
  float* partial = scale_e + 512 + 8192;   // 100*512 floats

  float* h_out = (float*)d_out;
  float* e_out = (float*)d_out + HN_;

  prelin_kernel<<<108, 256, 0, stream>>>(h, Uw, Ub, Vw, Vb, Aw, Ab, Bw, Bb, Cw,
                                         Uh, Vh, Ah, Bh, Cwf);
  hipMemsetAsync(agg, 0, (size_t)3 * HN_ * sizeof(float), stream);
  gemm_pass<0><<<BN_ * 4, 256, 0, stream>>>(e, Cwf, Cb, Ah, Bh, Vh,
                                            agg, psum, psumsq,
                                            nullptr, nullptr, nullptr);
  stats_part<<<100, 256, 0, stream>>>(psum, psumsq, Uh, agg, partial);
  stats_final<<<1, 128, 0, stream>>>(partial, gamma_h, beta_h, gamma_e, beta_e,
                                     scale_e, shift_e, scale_h, shift_h);
  hpath_kernel<<<200, 256, 0, stream>>>(h, Uh, agg, scale_h, shift_h, h_out);
  gemm_pass<1><<<BN_ * 4, 256, 0, stream>>>(e, Cwf, Cb, Ah, Bh, nullptr,
                                            nullptr, nullptr, nullptr,
                                            scale_e, shift_e, e_out);
}